// Round 12
// baseline (250.012 us; speedup 1.0000x reference)
//
#include <hip/hip_runtime.h>
#include <hip/hip_bf16.h>

// Problem constants
#define B_   4
#define T_   2048
#define C_   1024
#define H_   16
#define D_   64
#define NQKV 3072
#define M_   (B_*T_)

typedef __attribute__((ext_vector_type(8))) short bf16x8;   // 8 bf16 = 4 VGPR (MFMA A/B frag)
typedef __attribute__((ext_vector_type(4))) short bf16x4;   // 8B packed store
typedef __attribute__((ext_vector_type(4))) float f32x4;    // MFMA C/D frag
typedef __hip_bfloat16 bf16;

__device__ inline short f2bs(float f) {
    bf16 h = __float2bfloat16(f);
    return *(short*)&h;
}

// bare v_exp_f32 (2^x) — __exp2f does not exist in HIP headers
__device__ inline float exp2g(float f) { return __builtin_amdgcn_exp2f(f); }

// async global->LDS, 16B per lane. LDS dest must be wave-uniform base + lane*16.
__device__ inline void async_ld16(const bf16* g, const short* l) {
    __builtin_amdgcn_global_load_lds(
        (const __attribute__((address_space(1))) void*)g,
        (__attribute__((address_space(3))) void*)l, 16, 0, 0);
}

// ---------------- fused prep: cvt_x (blocks 0..4095), Wqkv^T (4096..7167),
//                  Wproj^T (7168..8191) ----------------
__global__ __launch_bounds__(256) void prep(const float* __restrict__ x,
                                            const float* __restrict__ Wqkv,
                                            const float* __restrict__ Wproj,
                                            bf16* __restrict__ xb,
                                            bf16* __restrict__ wqkv_t,
                                            bf16* __restrict__ wproj_t) {
    __shared__ short t[32][33];
    const int bid = blockIdx.x;
    if (bid < 4096) {
        const long i = ((long)bid * 256 + threadIdx.x) * 8;
        const float4 a = *(const float4*)(x + i);
        const float4 bq = *(const float4*)(x + i + 4);
        bf16x8 o;
        o[0] = f2bs(a.x); o[1] = f2bs(a.y); o[2] = f2bs(a.z); o[3] = f2bs(a.w);
        o[4] = f2bs(bq.x); o[5] = f2bs(bq.y); o[6] = f2bs(bq.z); o[7] = f2bs(bq.w);
        *(bf16x8*)(xb + i) = o;
        return;
    }
    const float* in;  bf16* out;  int R, Ccol, r0, c0;
    if (bid < 7168) {
        const int b2 = bid - 4096;            // Wqkv: [C,3C] -> [3C,C]
        in = Wqkv; out = wqkv_t; R = C_; Ccol = NQKV;
        c0 = (b2 % 96) * 32; r0 = (b2 / 96) * 32;
    } else {
        const int b3 = bid - 7168;            // Wproj: [C,C] -> [C,C]^T
        in = Wproj; out = wproj_t; R = C_; Ccol = C_;
        c0 = (b3 % 32) * 32; r0 = (b3 / 32) * 32;
    }
    const int xx = threadIdx.x & 31, yy = threadIdx.x >> 5;  // 32 x 8
#pragma unroll
    for (int i = 0; i < 4; i++)
        t[yy + 8*i][xx] = f2bs(in[(long)(r0 + yy + 8*i) * Ccol + c0 + xx]);
    __syncthreads();
#pragma unroll
    for (int i = 0; i < 4; i++)
        ((short*)out)[(long)(c0 + yy + 8*i) * R + r0 + xx] = t[xx][yy + 8*i];
}

// ---------------- GEMM: C[M,N] = A[M,K] * Bt[N,K]^T  (BK=64, global_load_lds) -----
// MODE 0: epilogue scatters bf16 to k/q; Q pre-scaled C^-0.5*log2(e);
//         V-segment blocks (n0>=2048) LDS-transpose -> V^T [B,H,D,T].
// MODE 1: epilogue stores fp32 to outp[M,N]
template<int MODE>
__global__ __launch_bounds__(256) void gemm_bt(const bf16* __restrict__ A,
                                               const bf16* __restrict__ Bt,
                                               float* __restrict__ outp,
                                               bf16* __restrict__ qb,
                                               bf16* __restrict__ kb,
                                               bf16* __restrict__ vbT,
                                               int K, int N) {
    // 36 KB union: K-loop uses As(16K)+Bs(16K); V-epilogue reuses as Vt[128][144]
    __shared__ __align__(16) short SMEM[18432];
    short* As = SMEM;            // [128 rows][64 k], chunk c8 stored at slot c8^(row&7)
    short* Bs = SMEM + 8192;
    const int tid  = threadIdx.x;
    const int w    = tid >> 6, lane = tid & 63;
    const int g    = lane >> 4, ln = lane & 15;
    const int m0   = blockIdx.y * 128, n0 = blockIdx.x * 128;
    const int wm   = w & 1, wn = w >> 1;           // wave quadrant (2x2 of 64x64)

    f32x4 acc[4][4] = {};

    for (int k0 = 0; k0 < K; k0 += 64) {
        // stage 128x64 A,B tiles: 4 chunk-issues per thread per operand.
#pragma unroll
        for (int i = 0; i < 4; i++) {
            const int s   = w * 256 + i * 64 + lane;
            const int row = s >> 3, c8 = (s & 7) ^ ((s >> 3) & 7);
            async_ld16(A  + (long)(m0 + row) * K + k0 + c8 * 8, &As[s * 8]);
            async_ld16(Bt + (long)(n0 + row) * K + k0 + c8 * 8, &Bs[s * 8]);
        }
        __syncthreads();   // drains vmcnt -> staging complete & visible

#pragma unroll
        for (int kh = 0; kh < 2; kh++) {
            bf16x8 af[4], bfr[4];
#pragma unroll
            for (int i = 0; i < 4; i++)
                af[i]  = *(const bf16x8*)&As[(wm * 64 + i * 16 + ln) * 64 + ((kh * 4 + g) ^ (ln & 7)) * 8];
#pragma unroll
            for (int j = 0; j < 4; j++)
                bfr[j] = *(const bf16x8*)&Bs[(wn * 64 + j * 16 + ln) * 64 + ((kh * 4 + g) ^ (ln & 7)) * 8];
#pragma unroll
            for (int i = 0; i < 4; i++)
#pragma unroll
                for (int j = 0; j < 4; j++)
                    acc[i][j] = __builtin_amdgcn_mfma_f32_16x16x32_bf16(af[i], bfr[j], acc[i][j], 0, 0, 0);
        }
        __syncthreads();   // fragment reads done before next tile's DMA overwrites
    }

    if (MODE == 0 && n0 >= 2048) {
        // ---- V segment: LDS-transpose tile, store V^T [B,H,D,T] with 16B stores ----
        short* Vt = SMEM;                       // [128 d_local][stride 144]
#pragma unroll
        for (int i = 0; i < 4; i++)
#pragma unroll
            for (int j = 0; j < 4; j++)
#pragma unroll
                for (int r = 0; r < 4; r++) {
                    const int tl = wm * 64 + i * 16 + g * 4 + r;   // t within tile
                    const int dl = wn * 64 + j * 16 + ln;          // d_local (2 heads)
                    Vt[dl * 144 + tl] = f2bs(acc[i][j][r]);
                }
        __syncthreads();
        const int b  = m0 >> 11, tb = m0 & (T_ - 1);
        const int h0 = (n0 - 2048) >> 6;
#pragma unroll
        for (int ii = 0; ii < 8; ii++) {
            const int s = ii * 256 + tid;       // 2048 chunks: 128 dl x 16 t-chunks
            const int dl = s >> 4, t16 = s & 15;
            const bf16x8 v = *(const bf16x8*)&Vt[dl * 144 + t16 * 8];
            const int h = h0 + (dl >> 6), d = dl & 63;
            *(bf16x8*)&vbT[(((long)(b * H_ + h)) * D_ + d) * T_ + tb + t16 * 8] = v;
        }
        return;
    }

#pragma unroll
    for (int i = 0; i < 4; i++) {
#pragma unroll
        for (int j = 0; j < 4; j++) {
#pragma unroll
            for (int r = 0; r < 4; r++) {
                const int row = m0 + wm * 64 + i * 16 + g * 4 + r;   // C/D: row = quad*4+reg
                const int col = n0 + wn * 64 + j * 16 + ln;          // C/D: col = lane&15
                if (MODE == 1) {
                    outp[(long)row * N + col] = acc[i][j][r];        // fp32 output
                } else {
                    const int b = row >> 11, t = row & (T_ - 1);
                    const int seg = col >> 10;                 // 0:K 1:Q (V handled above)
                    const int c = col & (C_ - 1), h = c >> 6, d = c & 63;
                    if (seg == 0)
                        kb[(((long)(b * H_ + h)) * T_ + t) * D_ + d] = __float2bfloat16(acc[i][j][r]);
                    else   // Q pre-scaled by C^-0.5 * log2(e): flash uses exp2
                        qb[(((long)(b * H_ + h)) * T_ + t) * D_ + d] =
                            __float2bfloat16(acc[i][j][r] * (0.03125f * 1.44269504f));
                }
            }
        }
    }
}

// ---------------- flash v13: v12 (4 Q-tiles, dbuf DMA staging) + QUAD-fused
//                  subtile in the all-active region: one set of kf reads feeds
//                  4 QK^T (saves 16 ds_read_b128/wave/h2), and the 4 P-stages
//                  form a 4-deep pipeline (PV_x covers P_{x+1}'s LDS drain —
//                  two more lgkm waits hidden than the 2x pair arrangement).
//                  Canary: WRITE_SIZE must stay ~16.4 MB (no spill; peak VGPR
//                  ~200 under the (256,2) 256 cap; occupancy grid-limited at
//                  2 blocks/CU regardless). ----------------

#define EXPW_P(sx, diag)                                                          \
    do {                                                                          \
        if (diag) {                                                               \
            _Pragma("unroll")                                                     \
            for (int kj = 0; kj < 4; kj++) {                                      \
                const int key = kbase + kj * 16 + ln;                             \
                _Pragma("unroll")                                                 \
                for (int r = 0; r < 4; r++) {                                     \
                    float p = exp2g(sx[kj][r]);                                   \
                    p = (key <= rowg + r) ? p : 0.f;                              \
                    const int prow = g * 4 + r;                                   \
                    const int pc8 = (kj * 2 + (ln >> 3)) ^ (prow & 7);            \
                    myP[prow * 64 + pc8 * 8 + (ln & 7)] = f2bs(p);                \
                }                                                                 \
            }                                                                     \
        } else {                                                                  \
            _Pragma("unroll")                                                     \
            for (int kj = 0; kj < 4; kj++)                                        \
                _Pragma("unroll")                                                 \
                for (int r = 0; r < 4; r++) {                                     \
                    const int prow = g * 4 + r;                                   \
                    const int pc8 = (kj * 2 + (ln >> 3)) ^ (prow & 7);            \
                    myP[prow * 64 + pc8 * 8 + (ln & 7)] = f2bs(exp2g(sx[kj][r])); \
                }                                                                 \
        }                                                                         \
    } while (0)

#define READ_P(pf0v, pf1v)                                                        \
    asm volatile("s_waitcnt lgkmcnt(0)" ::: "memory");                            \
    const bf16x8 pf0v = *(const bf16x8*)&myP[ln * 64 + ((0 + g) ^ (ln & 7)) * 8]; \
    const bf16x8 pf1v = *(const bf16x8*)&myP[ln * 64 + ((4 + g) ^ (ln & 7)) * 8];

#define PV(ox, pf0v, pf1v)                                                        \
    __builtin_amdgcn_s_setprio(1);                                                \
    _Pragma("unroll")                                                             \
    for (int nb = 0; nb < 4; nb++) {                                              \
        const int drow = nb * 16 + ln;                                            \
        const bf16x8 vf0 = *(const bf16x8*)&Vs[drow * 128 + ((h2 * 8 + 0 + g) ^ (drow & 7)) * 8]; \
        ox[nb] = __builtin_amdgcn_mfma_f32_16x16x32_bf16(vf0, pf0v, ox[nb], 0, 0, 0); \
        const bf16x8 vf1 = *(const bf16x8*)&Vs[drow * 128 + ((h2 * 8 + 4 + g) ^ (drow & 7)) * 8]; \
        ox[nb] = __builtin_amdgcn_mfma_f32_16x16x32_bf16(vf1, pf1v, ox[nb], 0, 0, 0); \
    }                                                                             \
    __builtin_amdgcn_s_setprio(0);

// B-only subtile (single active tile; handles its own diagonal)
__device__ inline void subtile(const bf16x8& qf0, const bf16x8& qf1,
                               f32x4* o, f32x4& l,
                               const short* Ks, const short* Vs, short* myP,
                               int q0, int kbase, int h2, int w, int g, int ln,
                               const bf16x8& ones) {
    f32x4 s[4] = {};
    __builtin_amdgcn_s_setprio(1);
#pragma unroll
    for (int kj = 0; kj < 4; kj++) {
        const int krow = h2 * 64 + kj * 16 + ln;
        const bf16x8 kf0 = *(const bf16x8*)&Ks[krow * 64 + ((0 + g) ^ (krow & 7)) * 8];
        s[kj] = __builtin_amdgcn_mfma_f32_16x16x32_bf16(qf0, kf0, s[kj], 0, 0, 0);
        const bf16x8 kf1 = *(const bf16x8*)&Ks[krow * 64 + ((4 + g) ^ (krow & 7)) * 8];
        s[kj] = __builtin_amdgcn_mfma_f32_16x16x32_bf16(qf1, kf1, s[kj], 0, 0, 0);
    }
    __builtin_amdgcn_s_setprio(0);
    const int rowg = q0 + w * 16 + g * 4;   // + r
    const bool diag = (kbase == q0);
    EXPW_P(s, diag);
    READ_P(pf0, pf1);
    l = __builtin_amdgcn_mfma_f32_16x16x32_bf16(ones, pf0, l, 0, 0, 0);
    l = __builtin_amdgcn_mfma_f32_16x16x32_bf16(ones, pf1, l, 0, 0, 0);
    PV(o, pf0, pf1);
}

// Pair-fused: first tile may be diagonal, second strictly below-diagonal.
__device__ inline void subtile_ab(const bf16x8& qfA0, const bf16x8& qfA1,
                                  const bf16x8& qfB0, const bf16x8& qfB1,
                                  f32x4* oA, f32x4& lA, f32x4* oB, f32x4& lB,
                                  const short* Ks, const short* Vs, short* myP,
                                  int q0A, int kbase, int h2, int w, int g, int ln,
                                  const bf16x8& ones, bool diagA) {
    f32x4 sA[4] = {}, sB[4] = {};
    __builtin_amdgcn_s_setprio(1);
#pragma unroll
    for (int kj = 0; kj < 4; kj++) {
        const int krow = h2 * 64 + kj * 16 + ln;
        const bf16x8 kf0 = *(const bf16x8*)&Ks[krow * 64 + ((0 + g) ^ (krow & 7)) * 8];
        const bf16x8 kf1 = *(const bf16x8*)&Ks[krow * 64 + ((4 + g) ^ (krow & 7)) * 8];
        sA[kj] = __builtin_amdgcn_mfma_f32_16x16x32_bf16(qfA0, kf0, sA[kj], 0, 0, 0);
        sA[kj] = __builtin_amdgcn_mfma_f32_16x16x32_bf16(qfA1, kf1, sA[kj], 0, 0, 0);
        sB[kj] = __builtin_amdgcn_mfma_f32_16x16x32_bf16(qfB0, kf0, sB[kj], 0, 0, 0);
        sB[kj] = __builtin_amdgcn_mfma_f32_16x16x32_bf16(qfB1, kf1, sB[kj], 0, 0, 0);
    }
    __builtin_amdgcn_s_setprio(0);
    const int rowg = q0A + w * 16 + g * 4;   // + r (mask only applies to tile A)
    EXPW_P(sA, diagA);
    READ_P(pfA0, pfA1);
    lA = __builtin_amdgcn_mfma_f32_16x16x32_bf16(ones, pfA0, lA, 0, 0, 0);
    lA = __builtin_amdgcn_mfma_f32_16x16x32_bf16(ones, pfA1, lA, 0, 0, 0);
    EXPW_P(sB, false);                        // WAR after pfA reads: in-order DS
    PV(oA, pfA0, pfA1);                       // covers P_B drain
    READ_P(pfB0, pfB1);
    lB = __builtin_amdgcn_mfma_f32_16x16x32_bf16(ones, pfB0, lB, 0, 0, 0);
    lB = __builtin_amdgcn_mfma_f32_16x16x32_bf16(ones, pfB1, lB, 0, 0, 0);
    PV(oB, pfB0, pfB1);
}

// Quad-fused: all four tiles active. kf read ONCE for 4 QK^T; 4-deep P pipeline
// (PV_x covers P_{x+1}'s write drain). Only tile A may be diagonal (pair gaps
// q0B-q0A, q0C-q0B, q0D-q0C all >= 64 rows for every j).
__device__ inline void subtile_quad(const bf16x8& qfA0, const bf16x8& qfA1,
                                    const bf16x8& qfB0, const bf16x8& qfB1,
                                    const bf16x8& qfC0, const bf16x8& qfC1,
                                    const bf16x8& qfD0, const bf16x8& qfD1,
                                    f32x4* oA, f32x4& lA, f32x4* oB, f32x4& lB,
                                    f32x4* oC, f32x4& lC, f32x4* oD, f32x4& lD,
                                    const short* Ks, const short* Vs, short* myP,
                                    int q0A, int kbase, int h2, int w, int g, int ln,
                                    const bf16x8& ones, bool diagA) {
    f32x4 sA[4] = {}, sB[4] = {}, sC[4] = {}, sD[4] = {};
    __builtin_amdgcn_s_setprio(1);
#pragma unroll
    for (int kj = 0; kj < 4; kj++) {
        const int krow = h2 * 64 + kj * 16 + ln;
        const bf16x8 kf0 = *(const bf16x8*)&Ks[krow * 64 + ((0 + g) ^ (krow & 7)) * 8];
        const bf16x8 kf1 = *(const bf16x8*)&Ks[krow * 64 + ((4 + g) ^ (krow & 7)) * 8];
        sA[kj] = __builtin_amdgcn_mfma_f32_16x16x32_bf16(qfA0, kf0, sA[kj], 0, 0, 0);
        sA[kj] = __builtin_amdgcn_mfma_f32_16x16x32_bf16(qfA1, kf1, sA[kj], 0, 0, 0);
        sB[kj] = __builtin_amdgcn_mfma_f32_16x16x32_bf16(qfB0, kf0, sB[kj], 0, 0, 0);
        sB[kj] = __builtin_amdgcn_mfma_f32_16x16x32_bf16(qfB1, kf1, sB[kj], 0, 0, 0);
        sC[kj] = __builtin_amdgcn_mfma_f32_16x16x32_bf16(qfC0, kf0, sC[kj], 0, 0, 0);
        sC[kj] = __builtin_amdgcn_mfma_f32_16x16x32_bf16(qfC1, kf1, sC[kj], 0, 0, 0);
        sD[kj] = __builtin_amdgcn_mfma_f32_16x16x32_bf16(qfD0, kf0, sD[kj], 0, 0, 0);
        sD[kj] = __builtin_amdgcn_mfma_f32_16x16x32_bf16(qfD1, kf1, sD[kj], 0, 0, 0);
    }
    __builtin_amdgcn_s_setprio(0);
    const int rowg = q0A + w * 16 + g * 4;   // + r (mask only applies to tile A)
    EXPW_P(sA, diagA);
    READ_P(pfA0, pfA1);
    lA = __builtin_amdgcn_mfma_f32_16x16x32_bf16(ones, pfA0, lA, 0, 0, 0);
    lA = __builtin_amdgcn_mfma_f32_16x16x32_bf16(ones, pfA1, lA, 0, 0, 0);
    EXPW_P(sB, false);                        // WAR after pfA reads
    PV(oA, pfA0, pfA1);                       // covers P_B drain
    READ_P(pfB0, pfB1);
    lB = __builtin_amdgcn_mfma_f32_16x16x32_bf16(ones, pfB0, lB, 0, 0, 0);
    lB = __builtin_amdgcn_mfma_f32_16x16x32_bf16(ones, pfB1, lB, 0, 0, 0);
    EXPW_P(sC, false);
    PV(oB, pfB0, pfB1);                       // covers P_C drain
    READ_P(pfC0, pfC1);
    lC = __builtin_amdgcn_mfma_f32_16x16x32_bf16(ones, pfC0, lC, 0, 0, 0);
    lC = __builtin_amdgcn_mfma_f32_16x16x32_bf16(ones, pfC1, lC, 0, 0, 0);
    EXPW_P(sD, false);
    PV(oC, pfC0, pfC1);                       // covers P_D drain
    READ_P(pfD0, pfD1);
    lD = __builtin_amdgcn_mfma_f32_16x16x32_bf16(ones, pfD0, lD, 0, 0, 0);
    lD = __builtin_amdgcn_mfma_f32_16x16x32_bf16(ones, pfD1, lD, 0, 0, 0);
    PV(oD, pfD0, pfD1);
}

// DMA-stage one 128-key K/V tile into the given LDS buffers (v6-proven
// addressing: XOR swizzle on the GLOBAL chunk index, linear LDS dest).
__device__ inline void stage_kv(const bf16* kbase_p, const bf16* vbase_p,
                                short* KsB, short* VsB, int k0, int tid) {
#pragma unroll
    for (int i = 0; i < 4; i++) {
        const int cc = i * 256 + tid;
        const int key = cc >> 3, kc8 = (cc & 7) ^ (key & 7);
        async_ld16(kbase_p + (long)(k0 + key) * D_ + kc8 * 8, &KsB[cc * 8]);
        const int d = cc >> 4, vc16 = (cc & 15) ^ (d & 7);
        async_ld16(vbase_p + (long)d * T_ + k0 + vc16 * 8, &VsB[cc * 8]);
    }
}

__global__ __launch_bounds__(256, 2) void flash(const bf16* __restrict__ qb,
                                                const bf16* __restrict__ kb,
                                                const bf16* __restrict__ vbT,
                                                bf16* __restrict__ att) {
    __shared__ __align__(16) short Ks[2][128 * 64];  // [key][d]  chunk^=key&7, dbuf
    __shared__ __align__(16) short Vs[2][64 * 128];  // [d][key]  chunk^=d&7,  dbuf
    __shared__ __align__(16) short Ps[4 * 16 * 64];  // per-wave [qrow][key] swizzled
    const int tid = threadIdx.x, w = tid >> 6, lane = tid & 63;
    const int g = lane >> 4, ln = lane & 15;
    const int lin = blockIdx.x;                      // 512 blocks
    const int bh = lin & 63, j = lin >> 6;           // j in [0,8)
    const int b = bh >> 4, h = bh & 15;
    // 4 Q-tiles: q0A < q0B < q0C < q0D with adjacent gaps >= 64 rows for all j.
    const int q0A = j * 64, q0B = (15 - j) * 64;
    const int q0C = (16 + j) * 64, q0D = (31 - j) * 64;

    // Q fragments (A-layout), pre-scaled by C^-0.5*log2e in gemm0
    const bf16* qpA = qb + ((long)bh * T_ + q0A + w * 16 + ln) * D_;
    const bf16* qpB = qb + ((long)bh * T_ + q0B + w * 16 + ln) * D_;
    const bf16* qpC = qb + ((long)bh * T_ + q0C + w * 16 + ln) * D_;
    const bf16* qpD = qb + ((long)bh * T_ + q0D + w * 16 + ln) * D_;
    const bf16x8 qfA0 = *(const bf16x8*)(qpA + g * 8);
    const bf16x8 qfA1 = *(const bf16x8*)(qpA + 32 + g * 8);
    const bf16x8 qfB0 = *(const bf16x8*)(qpB + g * 8);
    const bf16x8 qfB1 = *(const bf16x8*)(qpB + 32 + g * 8);
    const bf16x8 qfC0 = *(const bf16x8*)(qpC + g * 8);
    const bf16x8 qfC1 = *(const bf16x8*)(qpC + 32 + g * 8);
    const bf16x8 qfD0 = *(const bf16x8*)(qpD + g * 8);
    const bf16x8 qfD1 = *(const bf16x8*)(qpD + 32 + g * 8);

    bf16x8 ones;
#pragma unroll
    for (int i = 0; i < 8; i++) ones[i] = 0x3F80;    // bf16 1.0

    f32x4 oA[4] = {}, oB[4] = {}, oC[4] = {}, oD[4] = {};
    f32x4 lA = {}, lB = {}, lC = {}, lD = {};
    short* myP = &Ps[w * 16 * 64];

    const bf16* kbase_p = kb  + (long)bh * T_ * D_;
    const bf16* vbase_p = vbT + (long)bh * D_ * T_;

    const int nst = (q0D + 64 + 127) >> 7;           // stagings needed (D superset)
    // prologue: DMA tile 0 into buf 0; __syncthreads drains vmcnt -> visible
    stage_kv(kbase_p, vbase_p, Ks[0], Vs[0], 0, tid);
    __syncthreads();
    for (int s = 0; s < nst; s++) {
        const int k0 = s * 128;
        const int cur = s & 1;
        // dbuf: issue next tile's DMA into the other buffer BEFORE compute.
        if (s + 1 < nst)
            stage_kv(kbase_p, vbase_p, Ks[cur ^ 1], Vs[cur ^ 1], k0 + 128, tid);

#pragma unroll
        for (int h2 = 0; h2 < 2; h2++) {
            const int kbase = k0 + h2 * 64;
            if (kbase <= q0A + 63) {        // all four active -> quad-fuse
                subtile_quad(qfA0, qfA1, qfB0, qfB1, qfC0, qfC1, qfD0, qfD1,
                             oA, lA, oB, lB, oC, lC, oD, lD,
                             Ks[cur], Vs[cur], myP, q0A, kbase, h2, w, g, ln, ones,
                             kbase == q0A);
            } else if (kbase <= q0B + 63) { // B,C,D active
                subtile_ab(qfB0, qfB1, qfC0, qfC1, oB, lB, oC, lC,
                           Ks[cur], Vs[cur], myP, q0B, kbase, h2, w, g, ln, ones,
                           kbase == q0B);
                subtile(qfD0, qfD1, oD, lD, Ks[cur], Vs[cur], myP, q0D, kbase, h2, w, g, ln, ones);
            } else if (kbase <= q0C + 63) { // C,D active
                subtile_ab(qfC0, qfC1, qfD0, qfD1, oC, lC, oD, lD,
                           Ks[cur], Vs[cur], myP, q0C, kbase, h2, w, g, ln, ones,
                           kbase == q0C);
            } else if (kbase <= q0D + 63) { // D only
                subtile(qfD0, qfD1, oD, lD, Ks[cur], Vs[cur], myP, q0D, kbase, h2, w, g, ln, ones);
            }
        }
        // one barrier per tile: compiler-emitted vmcnt(0) drain (next tile
        // landed) + all waves done reading buf[cur] before it's overwritten.
        __syncthreads();
    }

    // ---- epilogue: O^T C-layout row=d local (g*4+r), col=q=ln; divide by l ----
#pragma unroll
    for (int ti = 0; ti < 4; ti++) {
        const f32x4* o = (ti == 0) ? oA : (ti == 1) ? oB : (ti == 2) ? oC : oD;
        const float lv = (ti == 0) ? lA[0] : (ti == 1) ? lB[0] : (ti == 2) ? lC[0] : lD[0];
        const int q0 = (ti == 0) ? q0A : (ti == 1) ? q0B : (ti == 2) ? q0C : q0D;
        const float invl = 1.f / lv;
        const int q = q0 + w * 16 + ln;
#pragma unroll
        for (int nb = 0; nb < 4; nb++) {
            bf16x4 pk;
#pragma unroll
            for (int r = 0; r < 4; r++) pk[r] = f2bs(o[nb][r] * invl);
            *(bf16x4*)&att[((long)b * T_ + q) * C_ + h * D_ + nb * 16 + g * 4] = pk;
        }
    }
}

// ---------------- launch ----------------
extern "C" void kernel_launch(void* const* d_in, const int* in_sizes, int n_in,
                              void* d_out, int out_size, void* d_ws, size_t ws_size,
                              hipStream_t stream) {
    const float* x     = (const float*)d_in[0];   // [B,T,C] fp32
    const float* Wqkv  = (const float*)d_in[1];   // [C,3C]  fp32
    const float* Wproj = (const float*)d_in[2];   // [C,C]   fp32
    float* out = (float*)d_out;                   // [B,T,C] fp32

    // Liveness-planned workspace (75.5 MB):
    //  att aliases xb (xb dead after gemm0; flash writes att after gemm0)
    char* ws = (char*)d_ws;
    bf16* wqkv_t  = (bf16*)(ws);                 // [3072,1024] bf16  6291456 B
    bf16* wproj_t = (bf16*)(ws + 6291456);       // [1024,1024] bf16  2097152 B
    bf16* qb      = (bf16*)(ws + 8388608);       // [B,H,T,D]   bf16 16777216 B
    bf16* kb      = (bf16*)(ws + 25165824);      // [B,H,T,D]   bf16 16777216 B
    bf16* vbT     = (bf16*)(ws + 41943040);      // [B,H,D,T]   bf16 16777216 B
    bf16* xb      = (bf16*)(ws + 58720256);      // [B,T,C]     bf16 16777216 B
    bf16* att     = xb;                          // alias (after gemm0)
    (void)ws_size; (void)in_sizes; (void)n_in; (void)out_size;

    prep<<<dim3(8192), dim3(256), 0, stream>>>(x, Wqkv, Wproj, xb, wqkv_t, wproj_t);
    gemm_bt<0><<<dim3(NQKV / 128, M_ / 128), dim3(256), 0, stream>>>(
        xb, wqkv_t, (float*)nullptr, qb, kb, vbT, C_, NQKV);
    flash<<<dim3(512), dim3(256), 0, stream>>>(qb, kb, vbT, att);
    gemm_bt<1><<<dim3(C_ / 128, M_ / 128), dim3(256), 0, stream>>>(
        att, wproj_t, out, (bf16*)nullptr, (bf16*)nullptr, (bf16*)nullptr, C_, C_);
}

// Round 13
// 236.806 us; speedup vs baseline: 1.0558x; 1.0558x over previous
//
#include <hip/hip_runtime.h>
#include <hip/hip_bf16.h>

// Problem constants
#define B_   4
#define T_   2048
#define C_   1024
#define H_   16
#define D_   64
#define NQKV 3072
#define M_   (B_*T_)

typedef __attribute__((ext_vector_type(8))) short bf16x8;   // 8 bf16 = 4 VGPR (MFMA A/B frag)
typedef __attribute__((ext_vector_type(4))) short bf16x4;   // 8B packed store
typedef __attribute__((ext_vector_type(4))) float f32x4;    // MFMA C/D frag
typedef __hip_bfloat16 bf16;

__device__ inline short f2bs(float f) {
    bf16 h = __float2bfloat16(f);
    return *(short*)&h;
}

// bare v_exp_f32 (2^x) — __exp2f does not exist in HIP headers
__device__ inline float exp2g(float f) { return __builtin_amdgcn_exp2f(f); }

// async global->LDS, 16B per lane. LDS dest must be wave-uniform base + lane*16.
__device__ inline void async_ld16(const bf16* g, const short* l) {
    __builtin_amdgcn_global_load_lds(
        (const __attribute__((address_space(1))) void*)g,
        (__attribute__((address_space(3))) void*)l, 16, 0, 0);
}

// ---------------- fused prep: cvt_x (blocks 0..4095), Wqkv^T (4096..7167),
//                  Wproj^T (7168..8191) ----------------
__global__ __launch_bounds__(256) void prep(const float* __restrict__ x,
                                            const float* __restrict__ Wqkv,
                                            const float* __restrict__ Wproj,
                                            bf16* __restrict__ xb,
                                            bf16* __restrict__ wqkv_t,
                                            bf16* __restrict__ wproj_t) {
    __shared__ short t[32][33];
    const int bid = blockIdx.x;
    if (bid < 4096) {
        const long i = ((long)bid * 256 + threadIdx.x) * 8;
        const float4 a = *(const float4*)(x + i);
        const float4 bq = *(const float4*)(x + i + 4);
        bf16x8 o;
        o[0] = f2bs(a.x); o[1] = f2bs(a.y); o[2] = f2bs(a.z); o[3] = f2bs(a.w);
        o[4] = f2bs(bq.x); o[5] = f2bs(bq.y); o[6] = f2bs(bq.z); o[7] = f2bs(bq.w);
        *(bf16x8*)(xb + i) = o;
        return;
    }
    const float* in;  bf16* out;  int R, Ccol, r0, c0;
    if (bid < 7168) {
        const int b2 = bid - 4096;            // Wqkv: [C,3C] -> [3C,C]
        in = Wqkv; out = wqkv_t; R = C_; Ccol = NQKV;
        c0 = (b2 % 96) * 32; r0 = (b2 / 96) * 32;
    } else {
        const int b3 = bid - 7168;            // Wproj: [C,C] -> [C,C]^T
        in = Wproj; out = wproj_t; R = C_; Ccol = C_;
        c0 = (b3 % 32) * 32; r0 = (b3 / 32) * 32;
    }
    const int xx = threadIdx.x & 31, yy = threadIdx.x >> 5;  // 32 x 8
#pragma unroll
    for (int i = 0; i < 4; i++)
        t[yy + 8*i][xx] = f2bs(in[(long)(r0 + yy + 8*i) * Ccol + c0 + xx]);
    __syncthreads();
#pragma unroll
    for (int i = 0; i < 4; i++)
        ((short*)out)[(long)(c0 + yy + 8*i) * R + r0 + xx] = t[xx][yy + 8*i];
}

// ---------------- GEMM: C[M,N] = A[M,K] * Bt[N,K]^T  (BK=64, global_load_lds) -----
// MODE 0: epilogue scatters bf16 to k/q (scalar stores); Q pre-scaled
//         C^-0.5*log2(e); V-segment blocks (n0>=2048) LDS-transpose -> V^T.
// MODE 1: epilogue stores fp32 to outp[M,N]
template<int MODE>
__global__ __launch_bounds__(256) void gemm_bt(const bf16* __restrict__ A,
                                               const bf16* __restrict__ Bt,
                                               float* __restrict__ outp,
                                               bf16* __restrict__ qb,
                                               bf16* __restrict__ kb,
                                               bf16* __restrict__ vbT,
                                               int K, int N) {
    // 36 KB union: K-loop uses As(16K)+Bs(16K); V-epilogue reuses as Vt[128][144]
    __shared__ __align__(16) short SMEM[18432];
    short* As = SMEM;            // [128 rows][64 k], chunk c8 stored at slot c8^(row&7)
    short* Bs = SMEM + 8192;
    const int tid  = threadIdx.x;
    const int w    = tid >> 6, lane = tid & 63;
    const int g    = lane >> 4, ln = lane & 15;
    const int m0   = blockIdx.y * 128, n0 = blockIdx.x * 128;
    const int wm   = w & 1, wn = w >> 1;           // wave quadrant (2x2 of 64x64)

    f32x4 acc[4][4] = {};

    for (int k0 = 0; k0 < K; k0 += 64) {
        // stage 128x64 A,B tiles: 4 chunk-issues per thread per operand.
        // LDS slot s -> row=s>>3, slot-chunk=s&7; global chunk = slot^(row&7) (swizzle
        // applied on the GLOBAL side so LDS dest stays uniform-base + lane*16).
#pragma unroll
        for (int i = 0; i < 4; i++) {
            const int s   = w * 256 + i * 64 + lane;
            const int row = s >> 3, c8 = (s & 7) ^ ((s >> 3) & 7);
            async_ld16(A  + (long)(m0 + row) * K + k0 + c8 * 8, &As[s * 8]);
            async_ld16(Bt + (long)(n0 + row) * K + k0 + c8 * 8, &Bs[s * 8]);
        }
        __syncthreads();   // drains vmcnt -> staging complete & visible

#pragma unroll
        for (int kh = 0; kh < 2; kh++) {
            bf16x8 af[4], bfr[4];
#pragma unroll
            for (int i = 0; i < 4; i++)
                af[i]  = *(const bf16x8*)&As[(wm * 64 + i * 16 + ln) * 64 + ((kh * 4 + g) ^ (ln & 7)) * 8];
#pragma unroll
            for (int j = 0; j < 4; j++)
                bfr[j] = *(const bf16x8*)&Bs[(wn * 64 + j * 16 + ln) * 64 + ((kh * 4 + g) ^ (ln & 7)) * 8];
#pragma unroll
            for (int i = 0; i < 4; i++)
#pragma unroll
                for (int j = 0; j < 4; j++)
                    acc[i][j] = __builtin_amdgcn_mfma_f32_16x16x32_bf16(af[i], bfr[j], acc[i][j], 0, 0, 0);
        }
        __syncthreads();   // fragment reads done before next tile's DMA overwrites
    }

    if (MODE == 0 && n0 >= 2048) {
        // ---- V segment: LDS-transpose tile, store V^T [B,H,D,T] with 16B stores ----
        short* Vt = SMEM;                       // [128 d_local][stride 144]
#pragma unroll
        for (int i = 0; i < 4; i++)
#pragma unroll
            for (int j = 0; j < 4; j++)
#pragma unroll
                for (int r = 0; r < 4; r++) {
                    const int tl = wm * 64 + i * 16 + g * 4 + r;   // t within tile
                    const int dl = wn * 64 + j * 16 + ln;          // d_local (2 heads)
                    Vt[dl * 144 + tl] = f2bs(acc[i][j][r]);
                }
        __syncthreads();
        const int b  = m0 >> 11, tb = m0 & (T_ - 1);
        const int h0 = (n0 - 2048) >> 6;
#pragma unroll
        for (int ii = 0; ii < 8; ii++) {
            const int s = ii * 256 + tid;       // 2048 chunks: 128 dl x 16 t-chunks
            const int dl = s >> 4, t16 = s & 15;
            const bf16x8 v = *(const bf16x8*)&Vt[dl * 144 + t16 * 8];
            const int h = h0 + (dl >> 6), d = dl & 63;
            *(bf16x8*)&vbT[(((long)(b * H_ + h)) * D_ + d) * T_ + tb + t16 * 8] = v;
        }
        return;
    }

#pragma unroll
    for (int i = 0; i < 4; i++) {
#pragma unroll
        for (int j = 0; j < 4; j++) {
#pragma unroll
            for (int r = 0; r < 4; r++) {
                const int row = m0 + wm * 64 + i * 16 + g * 4 + r;   // C/D: row = quad*4+reg
                const int col = n0 + wn * 64 + j * 16 + ln;          // C/D: col = lane&15
                if (MODE == 1) {
                    outp[(long)row * N + col] = acc[i][j][r];        // fp32 output
                } else {
                    const int b = row >> 11, t = row & (T_ - 1);
                    const int seg = col >> 10;                 // 0:K 1:Q (V handled above)
                    const int c = col & (C_ - 1), h = c >> 6, d = c & 63;
                    if (seg == 0)
                        kb[(((long)(b * H_ + h)) * T_ + t) * D_ + d] = __float2bfloat16(acc[i][j][r]);
                    else   // Q pre-scaled by C^-0.5 * log2(e): flash uses exp2
                        qb[(((long)(b * H_ + h)) * T_ + t) * D_ + d] =
                            __float2bfloat16(acc[i][j][r] * (0.03125f * 1.44269504f));
                }
            }
        }
    }
}

// ---------------- flash v12 (PROVEN BEST, round 11: flash 73.7 us, total 239.8):
//                  4 Q-tiles/block {j,15-j,16+j,31-j}, pair-fused subtiles,
//                  dbuf DMA staging (one barrier/tile), exp2, setprio,
//                  launch_bounds(256,2). Round-12 quad fusion REVERTED (spilled
//                  at the ~128-VGPR allocator wall: WRITE 16.4->18.9 MB,
//                  MfmaUtil 21->16, flash +20 us). ----------------

// B-only subtile (tile A finished)
__device__ inline void subtile(const bf16x8& qf0, const bf16x8& qf1,
                               f32x4* o, f32x4& l,
                               const short* Ks, const short* Vs, short* myP,
                               int q0, int kbase, int h2, int w, int g, int ln,
                               const bf16x8& ones) {
    f32x4 s[4] = {};
    __builtin_amdgcn_s_setprio(1);
#pragma unroll
    for (int kj = 0; kj < 4; kj++) {
        const int krow = h2 * 64 + kj * 16 + ln;
        const bf16x8 kf0 = *(const bf16x8*)&Ks[krow * 64 + ((0 + g) ^ (krow & 7)) * 8];
        s[kj] = __builtin_amdgcn_mfma_f32_16x16x32_bf16(qf0, kf0, s[kj], 0, 0, 0);
        const bf16x8 kf1 = *(const bf16x8*)&Ks[krow * 64 + ((4 + g) ^ (krow & 7)) * 8];
        s[kj] = __builtin_amdgcn_mfma_f32_16x16x32_bf16(qf1, kf1, s[kj], 0, 0, 0);
    }
    __builtin_amdgcn_s_setprio(0);
    const int rowg = q0 + w * 16 + g * 4;   // + r
    if (kbase == q0) {                      // diagonal sub-tile: causal mask
#pragma unroll
        for (int kj = 0; kj < 4; kj++) {
            const int key = kbase + kj * 16 + ln;
#pragma unroll
            for (int r = 0; r < 4; r++) {
                float p = exp2g(s[kj][r]);             // Q pre-scaled incl log2e
                p = (key <= rowg + r) ? p : 0.f;
                const int prow = g * 4 + r;
                const int pc8 = (kj * 2 + (ln >> 3)) ^ (prow & 7);
                myP[prow * 64 + pc8 * 8 + (ln & 7)] = f2bs(p);
            }
        }
    } else {                                // strictly-below-diagonal: unmasked
#pragma unroll
        for (int kj = 0; kj < 4; kj++) {
#pragma unroll
            for (int r = 0; r < 4; r++) {
                const int prow = g * 4 + r;
                const int pc8 = (kj * 2 + (ln >> 3)) ^ (prow & 7);
                myP[prow * 64 + pc8 * 8 + (ln & 7)] = f2bs(exp2g(s[kj][r]));
            }
        }
    }
    asm volatile("s_waitcnt lgkmcnt(0)" ::: "memory");   // wave-local P RAW
    const bf16x8 pf0 = *(const bf16x8*)&myP[ln * 64 + ((0 + g) ^ (ln & 7)) * 8];
    const bf16x8 pf1 = *(const bf16x8*)&myP[ln * 64 + ((4 + g) ^ (ln & 7)) * 8];
    l = __builtin_amdgcn_mfma_f32_16x16x32_bf16(ones, pf0, l, 0, 0, 0);
    l = __builtin_amdgcn_mfma_f32_16x16x32_bf16(ones, pf1, l, 0, 0, 0);
    __builtin_amdgcn_s_setprio(1);
#pragma unroll
    for (int nb = 0; nb < 4; nb++) {
        const int drow = nb * 16 + ln;
        const bf16x8 vf0 = *(const bf16x8*)&Vs[drow * 128 + ((h2 * 8 + 0 + g) ^ (drow & 7)) * 8];
        o[nb] = __builtin_amdgcn_mfma_f32_16x16x32_bf16(vf0, pf0, o[nb], 0, 0, 0);
        const bf16x8 vf1 = *(const bf16x8*)&Vs[drow * 128 + ((h2 * 8 + 4 + g) ^ (drow & 7)) * 8];
        o[nb] = __builtin_amdgcn_mfma_f32_16x16x32_bf16(vf1, pf1, o[nb], 0, 0, 0);
    }
    __builtin_amdgcn_s_setprio(0);
}

// Fused subtile: both tiles of a pair active. K fragments read ONCE and shared.
// Requires second tile strictly below-diagonal in the fused region (callers
// guarantee: pair gap >= 64 rows). Single myP buffer: WAR ordering safe under
// per-wave in-order DS.
__device__ inline void subtile_ab(const bf16x8& qfA0, const bf16x8& qfA1,
                                  const bf16x8& qfB0, const bf16x8& qfB1,
                                  f32x4* oA, f32x4& lA, f32x4* oB, f32x4& lB,
                                  const short* Ks, const short* Vs, short* myP,
                                  int q0A, int kbase, int h2, int w, int g, int ln,
                                  const bf16x8& ones, bool diagA) {
    f32x4 sA[4] = {}, sB[4] = {};
    __builtin_amdgcn_s_setprio(1);
#pragma unroll
    for (int kj = 0; kj < 4; kj++) {
        const int krow = h2 * 64 + kj * 16 + ln;
        const bf16x8 kf0 = *(const bf16x8*)&Ks[krow * 64 + ((0 + g) ^ (krow & 7)) * 8];
        const bf16x8 kf1 = *(const bf16x8*)&Ks[krow * 64 + ((4 + g) ^ (krow & 7)) * 8];
        sA[kj] = __builtin_amdgcn_mfma_f32_16x16x32_bf16(qfA0, kf0, sA[kj], 0, 0, 0);
        sA[kj] = __builtin_amdgcn_mfma_f32_16x16x32_bf16(qfA1, kf1, sA[kj], 0, 0, 0);
        sB[kj] = __builtin_amdgcn_mfma_f32_16x16x32_bf16(qfB0, kf0, sB[kj], 0, 0, 0);
        sB[kj] = __builtin_amdgcn_mfma_f32_16x16x32_bf16(qfB1, kf1, sB[kj], 0, 0, 0);
    }
    __builtin_amdgcn_s_setprio(0);
    // ---- exp + write P_A ----
    const int rowg = q0A + w * 16 + g * 4;   // + r
    if (diagA) {
#pragma unroll
        for (int kj = 0; kj < 4; kj++) {
            const int key = kbase + kj * 16 + ln;
#pragma unroll
            for (int r = 0; r < 4; r++) {
                float p = exp2g(sA[kj][r]);
                p = (key <= rowg + r) ? p : 0.f;
                const int prow = g * 4 + r;
                const int pc8 = (kj * 2 + (ln >> 3)) ^ (prow & 7);
                myP[prow * 64 + pc8 * 8 + (ln & 7)] = f2bs(p);
            }
        }
    } else {
#pragma unroll
        for (int kj = 0; kj < 4; kj++)
#pragma unroll
            for (int r = 0; r < 4; r++) {
                const int prow = g * 4 + r;
                const int pc8 = (kj * 2 + (ln >> 3)) ^ (prow & 7);
                myP[prow * 64 + pc8 * 8 + (ln & 7)] = f2bs(exp2g(sA[kj][r]));
            }
    }
    asm volatile("s_waitcnt lgkmcnt(0)" ::: "memory");   // P_A RAW
    const bf16x8 pfA0 = *(const bf16x8*)&myP[ln * 64 + ((0 + g) ^ (ln & 7)) * 8];
    const bf16x8 pfA1 = *(const bf16x8*)&myP[ln * 64 + ((4 + g) ^ (ln & 7)) * 8];
    lA = __builtin_amdgcn_mfma_f32_16x16x32_bf16(ones, pfA0, lA, 0, 0, 0);
    lA = __builtin_amdgcn_mfma_f32_16x16x32_bf16(ones, pfA1, lA, 0, 0, 0);
    // ---- exp + write P_B (WAR on myP after pfA reads: in-order DS) ----
#pragma unroll
    for (int kj = 0; kj < 4; kj++)
#pragma unroll
        for (int r = 0; r < 4; r++) {
            const int prow = g * 4 + r;
            const int pc8 = (kj * 2 + (ln >> 3)) ^ (prow & 7);
            myP[prow * 64 + pc8 * 8 + (ln & 7)] = f2bs(exp2g(sB[kj][r]));
        }
    // ---- PV_A: covers the P_B write drain ----
    __builtin_amdgcn_s_setprio(1);
#pragma unroll
    for (int nb = 0; nb < 4; nb++) {
        const int drow = nb * 16 + ln;
        const bf16x8 vf0 = *(const bf16x8*)&Vs[drow * 128 + ((h2 * 8 + 0 + g) ^ (drow & 7)) * 8];
        oA[nb] = __builtin_amdgcn_mfma_f32_16x16x32_bf16(vf0, pfA0, oA[nb], 0, 0, 0);
        const bf16x8 vf1 = *(const bf16x8*)&Vs[drow * 128 + ((h2 * 8 + 4 + g) ^ (drow & 7)) * 8];
        oA[nb] = __builtin_amdgcn_mfma_f32_16x16x32_bf16(vf1, pfA1, oA[nb], 0, 0, 0);
    }
    __builtin_amdgcn_s_setprio(0);
    asm volatile("s_waitcnt lgkmcnt(0)" ::: "memory");   // P_B RAW
    const bf16x8 pfB0 = *(const bf16x8*)&myP[ln * 64 + ((0 + g) ^ (ln & 7)) * 8];
    const bf16x8 pfB1 = *(const bf16x8*)&myP[ln * 64 + ((4 + g) ^ (ln & 7)) * 8];
    lB = __builtin_amdgcn_mfma_f32_16x16x32_bf16(ones, pfB0, lB, 0, 0, 0);
    lB = __builtin_amdgcn_mfma_f32_16x16x32_bf16(ones, pfB1, lB, 0, 0, 0);
    __builtin_amdgcn_s_setprio(1);
#pragma unroll
    for (int nb = 0; nb < 4; nb++) {
        const int drow = nb * 16 + ln;
        const bf16x8 vf0 = *(const bf16x8*)&Vs[drow * 128 + ((h2 * 8 + 0 + g) ^ (drow & 7)) * 8];
        oB[nb] = __builtin_amdgcn_mfma_f32_16x16x32_bf16(vf0, pfB0, oB[nb], 0, 0, 0);
        const bf16x8 vf1 = *(const bf16x8*)&Vs[drow * 128 + ((h2 * 8 + 4 + g) ^ (drow & 7)) * 8];
        oB[nb] = __builtin_amdgcn_mfma_f32_16x16x32_bf16(vf1, pfB1, oB[nb], 0, 0, 0);
    }
    __builtin_amdgcn_s_setprio(0);
}

// DMA-stage one 128-key K/V tile into the given LDS buffers (v6-proven
// addressing: XOR swizzle on the GLOBAL chunk index, linear LDS dest).
__device__ inline void stage_kv(const bf16* kbase_p, const bf16* vbase_p,
                                short* KsB, short* VsB, int k0, int tid) {
#pragma unroll
    for (int i = 0; i < 4; i++) {
        const int cc = i * 256 + tid;
        const int key = cc >> 3, kc8 = (cc & 7) ^ (key & 7);
        async_ld16(kbase_p + (long)(k0 + key) * D_ + kc8 * 8, &KsB[cc * 8]);
        const int d = cc >> 4, vc16 = (cc & 15) ^ (d & 7);
        async_ld16(vbase_p + (long)d * T_ + k0 + vc16 * 8, &VsB[cc * 8]);
    }
}

__global__ __launch_bounds__(256, 2) void flash(const bf16* __restrict__ qb,
                                                const bf16* __restrict__ kb,
                                                const bf16* __restrict__ vbT,
                                                bf16* __restrict__ att) {
    __shared__ __align__(16) short Ks[2][128 * 64];  // [key][d]  chunk^=key&7, dbuf
    __shared__ __align__(16) short Vs[2][64 * 128];  // [d][key]  chunk^=d&7,  dbuf
    __shared__ __align__(16) short Ps[4 * 16 * 64];  // per-wave [qrow][key] swizzled
    const int tid = threadIdx.x, w = tid >> 6, lane = tid & 63;
    const int g = lane >> 4, ln = lane & 15;
    const int lin = blockIdx.x;                      // 512 blocks
    const int bh = lin & 63, j = lin >> 6;           // j in [0,8)
    const int b = bh >> 4, h = bh & 15;
    // 4 Q-tiles: pairs (A,B) and (C,D); pair gap (15-2j)*64 >= 64 for all j.
    const int q0A = j * 64, q0B = (15 - j) * 64;
    const int q0C = (16 + j) * 64, q0D = (31 - j) * 64;

    // Q fragments (A-layout), pre-scaled by C^-0.5*log2e in gemm0
    const bf16* qpA = qb + ((long)bh * T_ + q0A + w * 16 + ln) * D_;
    const bf16* qpB = qb + ((long)bh * T_ + q0B + w * 16 + ln) * D_;
    const bf16* qpC = qb + ((long)bh * T_ + q0C + w * 16 + ln) * D_;
    const bf16* qpD = qb + ((long)bh * T_ + q0D + w * 16 + ln) * D_;
    const bf16x8 qfA0 = *(const bf16x8*)(qpA + g * 8);
    const bf16x8 qfA1 = *(const bf16x8*)(qpA + 32 + g * 8);
    const bf16x8 qfB0 = *(const bf16x8*)(qpB + g * 8);
    const bf16x8 qfB1 = *(const bf16x8*)(qpB + 32 + g * 8);
    const bf16x8 qfC0 = *(const bf16x8*)(qpC + g * 8);
    const bf16x8 qfC1 = *(const bf16x8*)(qpC + 32 + g * 8);
    const bf16x8 qfD0 = *(const bf16x8*)(qpD + g * 8);
    const bf16x8 qfD1 = *(const bf16x8*)(qpD + 32 + g * 8);

    bf16x8 ones;
#pragma unroll
    for (int i = 0; i < 8; i++) ones[i] = 0x3F80;    // bf16 1.0

    f32x4 oA[4] = {}, oB[4] = {}, oC[4] = {}, oD[4] = {};
    f32x4 lA = {}, lB = {}, lC = {}, lD = {};
    short* myP = &Ps[w * 16 * 64];

    const bf16* kbase_p = kb  + (long)bh * T_ * D_;
    const bf16* vbase_p = vbT + (long)bh * D_ * T_;

    const int nst = (q0D + 64 + 127) >> 7;           // stagings needed (D superset)
    // prologue: DMA tile 0 into buf 0; __syncthreads drains vmcnt -> visible
    stage_kv(kbase_p, vbase_p, Ks[0], Vs[0], 0, tid);
    __syncthreads();
    for (int s = 0; s < nst; s++) {
        const int k0 = s * 128;
        const int cur = s & 1;
        // T3 2-phase: issue next tile's DMA into the other buffer BEFORE compute.
        // Safe: buf[cur^1] was last read in iter s-1, joined by the barrier at
        // the end of s-1. Latency hides under this iter's subtile compute.
        if (s + 1 < nst)
            stage_kv(kbase_p, vbase_p, Ks[cur ^ 1], Vs[cur ^ 1], k0 + 128, tid);

#pragma unroll
        for (int h2 = 0; h2 < 2; h2++) {
            const int kbase = k0 + h2 * 64;
            if (kbase <= q0A + 63)          // A active => B active
                subtile_ab(qfA0, qfA1, qfB0, qfB1, oA, lA, oB, lB,
                           Ks[cur], Vs[cur], myP, q0A, kbase, h2, w, g, ln, ones,
                           kbase == q0A);
            else if (kbase <= q0B + 63)
                subtile(qfB0, qfB1, oB, lB, Ks[cur], Vs[cur], myP, q0B, kbase, h2, w, g, ln, ones);
            if (kbase <= q0C + 63)          // C active => D active
                subtile_ab(qfC0, qfC1, qfD0, qfD1, oC, lC, oD, lD,
                           Ks[cur], Vs[cur], myP, q0C, kbase, h2, w, g, ln, ones,
                           kbase == q0C);
            else if (kbase <= q0D + 63)
                subtile(qfD0, qfD1, oD, lD, Ks[cur], Vs[cur], myP, q0D, kbase, h2, w, g, ln, ones);
        }
        // one barrier per tile: compiler-emitted vmcnt(0) drain (next tile
        // landed) + all waves done reading buf[cur] before it's overwritten.
        __syncthreads();
    }

    // ---- epilogue: O^T C-layout row=d local (g*4+r), col=q=ln; divide by l ----
#pragma unroll
    for (int ti = 0; ti < 4; ti++) {
        const f32x4* o = (ti == 0) ? oA : (ti == 1) ? oB : (ti == 2) ? oC : oD;
        const float lv = (ti == 0) ? lA[0] : (ti == 1) ? lB[0] : (ti == 2) ? lC[0] : lD[0];
        const int q0 = (ti == 0) ? q0A : (ti == 1) ? q0B : (ti == 2) ? q0C : q0D;
        const float invl = 1.f / lv;
        const int q = q0 + w * 16 + ln;
#pragma unroll
        for (int nb = 0; nb < 4; nb++) {
            bf16x4 pk;
#pragma unroll
            for (int r = 0; r < 4; r++) pk[r] = f2bs(o[nb][r] * invl);
            *(bf16x4*)&att[((long)b * T_ + q) * C_ + h * D_ + nb * 16 + g * 4] = pk;
        }
    }
}

// ---------------- launch ----------------
extern "C" void kernel_launch(void* const* d_in, const int* in_sizes, int n_in,
                              void* d_out, int out_size, void* d_ws, size_t ws_size,
                              hipStream_t stream) {
    const float* x     = (const float*)d_in[0];   // [B,T,C] fp32
    const float* Wqkv  = (const float*)d_in[1];   // [C,3C]  fp32
    const float* Wproj = (const float*)d_in[2];   // [C,C]   fp32
    float* out = (float*)d_out;                   // [B,T,C] fp32

    // Liveness-planned workspace (75.5 MB):
    //  att aliases xb (xb dead after gemm0; flash writes att after gemm0)
    char* ws = (char*)d_ws;
    bf16* wqkv_t  = (bf16*)(ws);                 // [3072,1024] bf16  6291456 B
    bf16* wproj_t = (bf16*)(ws + 6291456);       // [1024,1024] bf16  2097152 B
    bf16* qb      = (bf16*)(ws + 8388608);       // [B,H,T,D]   bf16 16777216 B
    bf16* kb      = (bf16*)(ws + 25165824);      // [B,H,T,D]   bf16 16777216 B
    bf16* vbT     = (bf16*)(ws + 41943040);      // [B,H,D,T]   bf16 16777216 B
    bf16* xb      = (bf16*)(ws + 58720256);      // [B,T,C]     bf16 16777216 B
    bf16* att     = xb;                          // alias (after gemm0)
    (void)ws_size; (void)in_sizes; (void)n_in; (void)out_size;

    prep<<<dim3(8192), dim3(256), 0, stream>>>(x, Wqkv, Wproj, xb, wqkv_t, wproj_t);
    gemm_bt<0><<<dim3(NQKV / 128, M_ / 128), dim3(256), 0, stream>>>(
        xb, wqkv_t, (float*)nullptr, qb, kb, vbT, C_, NQKV);
    flash<<<dim3(512), dim3(256), 0, stream>>>(qb, kb, vbT, att);
    gemm_bt<1><<<dim3(C_ / 128, M_ / 128), dim3(256), 0, stream>>>(
        att, wproj_t, out, (bf16*)nullptr, (bf16*)nullptr, (bf16*)nullptr, C_, C_);
}